// Round 2
// baseline (203.256 us; speedup 1.0000x reference)
//
#include <hip/hip_runtime.h>

#define NODE 2048
#define KDIM 2048
#define CLUSTER 32
#define IN_DIM 64
#define OUT_DIM 64
#define BATCH 32

typedef short short8 __attribute__((ext_vector_type(8)));
typedef float f32x4 __attribute__((ext_vector_type(4)));

__device__ __forceinline__ short f2bf(float f) {
  unsigned u = __float_as_uint(f);
  u += 0x7fffu + ((u >> 16) & 1u);   // round-to-nearest-even
  return (short)(u >> 16);
}
__device__ __forceinline__ float bf2f(short s) {
  return __uint_as_float(((unsigned)(unsigned short)s) << 16);
}

// ---------------------------------------------------------------------------
// k1: w = alpha @ beta, stored as bf16 in MFMA-B fragment layout
//     w_frag[n][i>>3][o][i&7]  (short8 granule = 8 consecutive i for fixed o)
// grid 512: block = (8 nodes) x (half of i); thread = (o, i-group)
// ---------------------------------------------------------------------------
__global__ __launch_bounds__(256) void k1_wgen(
    const float* __restrict__ alpha, const float* __restrict__ beta,
    short8* __restrict__ w_frag) {
  const int bid = blockIdx.x;
  const int ngrp = bid >> 1;
  const int ihalf = bid & 1;
  const int t = threadIdx.x;
  const int o = t & 63;
  const int igl = t >> 6;              // 0..3
  const int i0 = ihalf * 32 + igl * 8; // this thread's 8 consecutive i
  const int n0 = ngrp * 8;

  float acc[8][8];
#pragma unroll
  for (int r = 0; r < 8; ++r)
#pragma unroll
    for (int j = 0; j < 8; ++j) acc[r][j] = 0.f;

  for (int k = 0; k < CLUSTER; ++k) {
    float av[8];
#pragma unroll
    for (int r = 0; r < 8; ++r) av[r] = alpha[(n0 + r) * CLUSTER + k];
    const float* bp = beta + k * (IN_DIM * OUT_DIM) + i0 * OUT_DIM + o;
#pragma unroll
    for (int j = 0; j < 8; ++j) {
      float bv = bp[j * OUT_DIM];
#pragma unroll
      for (int r = 0; r < 8; ++r) acc[r][j] += av[r] * bv;
    }
  }
#pragma unroll
  for (int r = 0; r < 8; ++r) {
    short8 s;
#pragma unroll
    for (int j = 0; j < 8; ++j) s[j] = f2bf(acc[r][j]);
    w_frag[((n0 + r) * 8 + (i0 >> 3)) * 64 + o] = s;
  }
}

// ---------------------------------------------------------------------------
// k2: h2[b,n,o] = sum_i h[b,n,i]*w[n,i,o] + bias[o]
// One wave per node n. Output stored bf16 in frag layout h2_frag[b][m>>3][o][m&7].
// ---------------------------------------------------------------------------
__global__ __launch_bounds__(64) void k2_h2(
    const float* __restrict__ h, const short8* __restrict__ w_frag,
    const float* __restrict__ bias, short* __restrict__ h2_frag) {
  const int n = blockIdx.x;
  const int l = threadIdx.x;
  const int lr = l & 15, lk = l >> 4;

  // A fragments: lane holds h[row=m*16+lr][n][k = kf*32 + lk*8 + j]
  short8 afr[2][2];
#pragma unroll
  for (int m = 0; m < 2; ++m)
#pragma unroll
    for (int kf = 0; kf < 2; ++kf) {
      const float* hp =
          h + ((size_t)(m * 16 + lr) * NODE + n) * IN_DIM + kf * 32 + lk * 8;
      f32x4 v0 = __builtin_nontemporal_load((const f32x4*)hp);
      f32x4 v1 = __builtin_nontemporal_load((const f32x4*)(hp + 4));
      short8 s;
#pragma unroll
      for (int j = 0; j < 4; ++j) { s[j] = f2bf(v0[j]); s[j + 4] = f2bf(v1[j]); }
      afr[m][kf] = s;
    }

  // B fragments straight from fragment-layout w (read exactly once globally)
  short8 bfr[4][2];
#pragma unroll
  for (int ng = 0; ng < 4; ++ng)
#pragma unroll
    for (int kf = 0; kf < 2; ++kf)
      bfr[ng][kf] = __builtin_nontemporal_load(
          &w_frag[(n * 8 + kf * 4 + lk) * 64 + ng * 16 + lr]);

  f32x4 acc[2][4];
#pragma unroll
  for (int m = 0; m < 2; ++m)
#pragma unroll
    for (int ng = 0; ng < 4; ++ng) acc[m][ng] = (f32x4){0.f, 0.f, 0.f, 0.f};

#pragma unroll
  for (int kf = 0; kf < 2; ++kf)
#pragma unroll
    for (int m = 0; m < 2; ++m)
#pragma unroll
      for (int ng = 0; ng < 4; ++ng)
        acc[m][ng] = __builtin_amdgcn_mfma_f32_16x16x32_bf16(
            afr[m][kf], bfr[ng][kf], acc[m][ng], 0, 0, 0);

#pragma unroll
  for (int m = 0; m < 2; ++m)
#pragma unroll
    for (int ng = 0; ng < 4; ++ng) {
      const int o = ng * 16 + lr;
      const float bv = bias[o];
#pragma unroll
      for (int r = 0; r < 4; ++r) {
        const int b = m * 16 + lk * 4 + r;  // D row = batch
        h2_frag[(((size_t)b * 256 + (n >> 3)) * 64 + o) * 8 + (n & 7)] =
            f2bf(acc[m][ng][r] + bv);
      }
    }
}

// ---------------------------------------------------------------------------
// k3 (hot): out[b] = a[b] @ h2[b] + h2[b]
// 1024 blocks x 256 thr (4 waves), BM=64; wave owns 16 rows (1 m-frag x 4
// n-frags). A: NONTEMPORAL global f32 -> bf16 in-register (A has zero reuse —
// keep L2 for the h2 panel). B: 16B frag loads from h2_frag (L2-resident per
// XCD: swizzle clusters the 32 same-batch blocks, 4 batches = 1 MiB/XCD).
// Register double-buffered K pipeline, no LDS, no barriers. 4 blocks/CU.
// ---------------------------------------------------------------------------
__global__ __launch_bounds__(256, 4) void k3_main(
    const float* __restrict__ a, const short* __restrict__ h2f,
    float* __restrict__ out) {
  const int bid0 = blockIdx.x;                     // 1024
  const int swz = (bid0 & 7) * 128 + (bid0 >> 3);  // XCD-cluster same-batch
  const int b = swz >> 5;                          // 32 batches
  const int rt = swz & 31;                         // 32 row tiles of 64
  const int t = threadIdx.x;
  const int wid = t >> 6;
  const int l = t & 63;
  const int lr = l & 15, lk = l >> 4;
  const int rowbase = rt * 64 + wid * 16;

  const float* ap =
      a + (size_t)b * NODE * KDIM + (size_t)(rowbase + lr) * KDIM + lk * 8;
  const short8* bbase = (const short8*)h2f + ((size_t)b * 256 + lk) * 64 + lr;

  f32x4 acc[4];
#pragma unroll
  for (int ng = 0; ng < 4; ++ng) acc[ng] = (f32x4){0.f, 0.f, 0.f, 0.f};

  f32x4 aA[2], aB[2];
  short8 bA[4], bB[4];

#define LOADK(k0, AR, BR)                                                     \
  do {                                                                        \
    const float* p_ = ap + (k0);                                              \
    AR[0] = __builtin_nontemporal_load((const f32x4*)p_);                     \
    AR[1] = __builtin_nontemporal_load((const f32x4*)(p_ + 4));               \
    const short8* q_ = bbase + ((k0) >> 3) * 64;                              \
    _Pragma("unroll") for (int ng_ = 0; ng_ < 4; ++ng_) BR[ng_] = q_[ng_ * 16]; \
  } while (0)

#define MFMASTEP(AR, BR)                                                      \
  do {                                                                        \
    short8 afr_;                                                              \
    _Pragma("unroll") for (int j_ = 0; j_ < 4; ++j_) {                        \
      afr_[j_] = f2bf(AR[0][j_]);                                             \
      afr_[j_ + 4] = f2bf(AR[1][j_]);                                         \
    }                                                                         \
    _Pragma("unroll") for (int ng_ = 0; ng_ < 4; ++ng_)                       \
      acc[ng_] = __builtin_amdgcn_mfma_f32_16x16x32_bf16(                     \
          afr_, BR[ng_], acc[ng_], 0, 0, 0);                                  \
  } while (0)

  LOADK(0, aA, bA);
#pragma unroll 1
  for (int k0 = 0; k0 < KDIM; k0 += 64) {
    LOADK(k0 + 32, aB, bB);
    MFMASTEP(aA, bA);
    if (k0 + 64 < KDIM) LOADK(k0 + 64, aA, bA);
    MFMASTEP(aB, bB);
  }
#undef LOADK
#undef MFMASTEP

  // epilogue: residual (+h2) fused, read from bf16 fragment buffer (L2-hot);
  // out written nontemporal (never re-read)
#pragma unroll
  for (int ng = 0; ng < 4; ++ng) {
    const int col = ng * 16 + lr;
#pragma unroll
    for (int r = 0; r < 4; ++r) {
      const int row = rowbase + lk * 4 + r;
      float resid =
          bf2f(h2f[(((size_t)b * 256 + (row >> 3)) * 64 + col) * 8 + (row & 7)]);
      __builtin_nontemporal_store(acc[ng][r] + resid,
                                  &out[((size_t)b * NODE + row) * 64 + col]);
    }
  }
}

extern "C" void kernel_launch(void* const* d_in, const int* in_sizes, int n_in,
                              void* d_out, int out_size, void* d_ws, size_t ws_size,
                              hipStream_t stream) {
  const float* a     = (const float*)d_in[0];
  const float* h     = (const float*)d_in[1];
  const float* alpha = (const float*)d_in[2];
  const float* beta  = (const float*)d_in[3];
  const float* bias  = (const float*)d_in[4];
  float* out = (float*)d_out;

  // workspace: w_frag bf16 16 MiB @ 0, h2_frag bf16 8 MiB @ 16 MiB
  short8* w_frag = (short8*)d_ws;
  short*  h2_frag = (short*)((char*)d_ws + (size_t)(16u << 20));

  k1_wgen<<<dim3(512), dim3(256), 0, stream>>>(alpha, beta, w_frag);
  k2_h2 <<<dim3(NODE), dim3(64),  0, stream>>>(h, w_frag, bias, h2_frag);
  k3_main<<<dim3(1024), dim3(256), 0, stream>>>(a, h2_frag, out);
}

// Round 3
// 188.551 us; speedup vs baseline: 1.0780x; 1.0780x over previous
//
#include <hip/hip_runtime.h>

#define NODE 2048
#define KDIM 2048
#define CLUSTER 32
#define IN_DIM 64
#define OUT_DIM 64
#define BATCH 32

typedef short short8 __attribute__((ext_vector_type(8)));
typedef short short4v __attribute__((ext_vector_type(4)));
typedef float f32x4 __attribute__((ext_vector_type(4)));

__device__ __forceinline__ short f2bf(float f) {
  unsigned u = __float_as_uint(f);
  u += 0x7fffu + ((u >> 16) & 1u);   // round-to-nearest-even
  return (short)(u >> 16);
}
__device__ __forceinline__ float bf2f(short s) {
  return __uint_as_float(((unsigned)(unsigned short)s) << 16);
}

// ---------------------------------------------------------------------------
// k1: w = alpha @ beta, stored as bf16 in MFMA-B fragment layout
//     w_frag[n][i>>3][o][i&7]
// ---------------------------------------------------------------------------
__global__ __launch_bounds__(256) void k1_wgen(
    const float* __restrict__ alpha, const float* __restrict__ beta,
    short8* __restrict__ w_frag) {
  const int bid = blockIdx.x;
  const int ngrp = bid >> 1;
  const int ihalf = bid & 1;
  const int t = threadIdx.x;
  const int o = t & 63;
  const int igl = t >> 6;
  const int i0 = ihalf * 32 + igl * 8;
  const int n0 = ngrp * 8;

  float acc[8][8];
#pragma unroll
  for (int r = 0; r < 8; ++r)
#pragma unroll
    for (int j = 0; j < 8; ++j) acc[r][j] = 0.f;

  for (int k = 0; k < CLUSTER; ++k) {
    float av[8];
#pragma unroll
    for (int r = 0; r < 8; ++r) av[r] = alpha[(n0 + r) * CLUSTER + k];
    const float* bp = beta + k * (IN_DIM * OUT_DIM) + i0 * OUT_DIM + o;
#pragma unroll
    for (int j = 0; j < 8; ++j) {
      float bv = bp[j * OUT_DIM];
#pragma unroll
      for (int r = 0; r < 8; ++r) acc[r][j] += av[r] * bv;
    }
  }
#pragma unroll
  for (int r = 0; r < 8; ++r) {
    short8 s;
#pragma unroll
    for (int j = 0; j < 8; ++j) s[j] = f2bf(acc[r][j]);
    w_frag[((n0 + r) * 8 + (i0 >> 3)) * 64 + o] = s;
  }
}

// ---------------------------------------------------------------------------
// k2: h2[b,n,o] = sum_i h[b,n,i]*w[n,i,o] + bias[o]
// One wave per node n. Output bf16 in frag layout h2_frag[b][m>>3][o][m&7].
// (plain loads — NT reverted)
// ---------------------------------------------------------------------------
__global__ __launch_bounds__(64) void k2_h2(
    const float* __restrict__ h, const short8* __restrict__ w_frag,
    const float* __restrict__ bias, short* __restrict__ h2_frag) {
  const int n = blockIdx.x;
  const int l = threadIdx.x;
  const int lr = l & 15, lk = l >> 4;

  short8 afr[2][2];
#pragma unroll
  for (int m = 0; m < 2; ++m)
#pragma unroll
    for (int kf = 0; kf < 2; ++kf) {
      const float* hp =
          h + ((size_t)(m * 16 + lr) * NODE + n) * IN_DIM + kf * 32 + lk * 8;
      f32x4 v0 = *(const f32x4*)hp;
      f32x4 v1 = *(const f32x4*)(hp + 4);
      short8 s;
#pragma unroll
      for (int j = 0; j < 4; ++j) { s[j] = f2bf(v0[j]); s[j + 4] = f2bf(v1[j]); }
      afr[m][kf] = s;
    }

  short8 bfr[4][2];
#pragma unroll
  for (int ng = 0; ng < 4; ++ng)
#pragma unroll
    for (int kf = 0; kf < 2; ++kf)
      bfr[ng][kf] = w_frag[(n * 8 + kf * 4 + lk) * 64 + ng * 16 + lr];

  f32x4 acc[2][4];
#pragma unroll
  for (int m = 0; m < 2; ++m)
#pragma unroll
    for (int ng = 0; ng < 4; ++ng) acc[m][ng] = (f32x4){0.f, 0.f, 0.f, 0.f};

#pragma unroll
  for (int kf = 0; kf < 2; ++kf)
#pragma unroll
    for (int m = 0; m < 2; ++m)
#pragma unroll
      for (int ng = 0; ng < 4; ++ng)
        acc[m][ng] = __builtin_amdgcn_mfma_f32_16x16x32_bf16(
            afr[m][kf], bfr[ng][kf], acc[m][ng], 0, 0, 0);

#pragma unroll
  for (int m = 0; m < 2; ++m)
#pragma unroll
    for (int ng = 0; ng < 4; ++ng) {
      const int o = ng * 16 + lr;
      const float bv = bias[o];
#pragma unroll
      for (int r = 0; r < 4; ++r) {
        const int b = m * 16 + lk * 4 + r;
        h2_frag[(((size_t)b * 256 + (n >> 3)) * 64 + o) * 8 + (n & 7)] =
            f2bf(acc[m][ng][r] + bv);
      }
    }
}

// ---------------------------------------------------------------------------
// k3 (hot): out[b] = a[b] @ h2[b] + h2[b]
// 512 blocks x 256 thr (4 waves), BM=128; wave owns 32 rows (2 m x 4 n frags).
// Depth-4 register pipeline for BOTH A (HBM) and B (L2): vmcnt retires in
// issue order, so B must be as deep as A or waits on B drain the A pipe.
// ~18 KiB in flight per wave at every wait; no LDS, no barriers.
// ---------------------------------------------------------------------------
__global__ __launch_bounds__(256, 2) void k3_main(
    const float* __restrict__ a, const short* __restrict__ h2f,
    float* __restrict__ out) {
  const int bid0 = blockIdx.x;                    // 512
  const int swz = (bid0 & 7) * 64 + (bid0 >> 3);  // XCD-cluster same-batch
  const int b = swz >> 4;                         // 32 batches
  const int rt = swz & 15;                        // 16 row tiles of 128
  const int t = threadIdx.x;
  const int wid = t >> 6;
  const int l = t & 63;
  const int lr = l & 15, lk = l >> 4;
  const int rowbase = rt * 128 + wid * 32;

  const float* ap0 =
      a + (size_t)b * NODE * KDIM + (size_t)(rowbase + lr) * KDIM + lk * 8;
  const float* ap1 = ap0 + (size_t)16 * KDIM;
  const short8* bbase = (const short8*)h2f + ((size_t)b * 256 + lk) * 64 + lr;

  f32x4 acc[2][4];
#pragma unroll
  for (int m = 0; m < 2; ++m)
#pragma unroll
    for (int ng = 0; ng < 4; ++ng) acc[m][ng] = (f32x4){0.f, 0.f, 0.f, 0.f};

  // 4-deep rotating buffers (named, static indexing only)
  f32x4 A0[4], A1[4], A2[4], A3[4];   // [m0.lo, m0.hi, m1.lo, m1.hi]
  short8 B0[4], B1[4], B2[4], B3[4];

#define LOADA(s, AR)                                             \
  do {                                                           \
    const int k_ = ((s) & 63) << 5;                              \
    AR[0] = *(const f32x4*)(ap0 + k_);                           \
    AR[1] = *(const f32x4*)(ap0 + k_ + 4);                       \
    AR[2] = *(const f32x4*)(ap1 + k_);                           \
    AR[3] = *(const f32x4*)(ap1 + k_ + 4);                       \
  } while (0)

#define LOADB(s, BR)                                             \
  do {                                                           \
    const int k_ = ((s) & 63) << 5;                              \
    const short8* q_ = bbase + (k_ >> 3) * 64;                   \
    BR[0] = q_[0];                                               \
    BR[1] = q_[16];                                              \
    BR[2] = q_[32];                                              \
    BR[3] = q_[48];                                              \
  } while (0)

#define STEP(AR, BR)                                                        \
  do {                                                                      \
    short8 af0_, af1_;                                                      \
    _Pragma("unroll") for (int j_ = 0; j_ < 4; ++j_) {                      \
      af0_[j_] = f2bf(AR[0][j_]);                                           \
      af0_[j_ + 4] = f2bf(AR[1][j_]);                                       \
      af1_[j_] = f2bf(AR[2][j_]);                                           \
      af1_[j_ + 4] = f2bf(AR[3][j_]);                                       \
    }                                                                       \
    _Pragma("unroll") for (int ng_ = 0; ng_ < 4; ++ng_) {                   \
      acc[0][ng_] = __builtin_amdgcn_mfma_f32_16x16x32_bf16(                \
          af0_, BR[ng_], acc[0][ng_], 0, 0, 0);                             \
      acc[1][ng_] = __builtin_amdgcn_mfma_f32_16x16x32_bf16(                \
          af1_, BR[ng_], acc[1][ng_], 0, 0, 0);                             \
    }                                                                       \
  } while (0)

  LOADA(0, A0); LOADB(0, B0);
  LOADA(1, A1); LOADB(1, B1);
  LOADA(2, A2); LOADB(2, B2);

#pragma unroll 1
  for (int s = 0; s < 64; s += 4) {
    LOADA(s + 3, A3); LOADB(s + 3, B3); STEP(A0, B0);
    LOADA(s + 4, A0); LOADB(s + 4, B0); STEP(A1, B1);
    LOADA(s + 5, A1); LOADB(s + 5, B1); STEP(A2, B2);
    LOADA(s + 6, A2); LOADB(s + 6, B2); STEP(A3, B3);
  }
#undef LOADA
#undef LOADB
#undef STEP

  // epilogue: residual (+h2) fused; 8-B vector residual reads (4 consecutive
  // m-slots share one short4 granule)
#pragma unroll
  for (int m = 0; m < 2; ++m) {
    const int row0 = rowbase + m * 16 + lk * 4;
#pragma unroll
    for (int ng = 0; ng < 4; ++ng) {
      const int col = ng * 16 + lr;
      const short4v rv = *(const short4v*)&h2f[
          (((size_t)b * 256 + (row0 >> 3)) * 64 + col) * 8 + (row0 & 7)];
#pragma unroll
      for (int r = 0; r < 4; ++r) {
        out[((size_t)b * NODE + row0 + r) * 64 + col] =
            acc[m][ng][r] + bf2f(rv[r]);
      }
    }
  }
}

extern "C" void kernel_launch(void* const* d_in, const int* in_sizes, int n_in,
                              void* d_out, int out_size, void* d_ws, size_t ws_size,
                              hipStream_t stream) {
  const float* a     = (const float*)d_in[0];
  const float* h     = (const float*)d_in[1];
  const float* alpha = (const float*)d_in[2];
  const float* beta  = (const float*)d_in[3];
  const float* bias  = (const float*)d_in[4];
  float* out = (float*)d_out;

  short8* w_frag = (short8*)d_ws;
  short*  h2_frag = (short*)((char*)d_ws + (size_t)(16u << 20));

  k1_wgen<<<dim3(512), dim3(256), 0, stream>>>(alpha, beta, w_frag);
  k2_h2 <<<dim3(NODE), dim3(64),  0, stream>>>(h, w_frag, bias, h2_frag);
  k3_main<<<dim3(512), dim3(256), 0, stream>>>(a, h2_frag, out);
}

// Round 4
// 173.974 us; speedup vs baseline: 1.1683x; 1.0838x over previous
//
#include <hip/hip_runtime.h>

#define NODE 2048
#define KDIM 2048
#define CLUSTER 32
#define IN_DIM 64
#define OUT_DIM 64
#define BATCH 32

typedef short short8 __attribute__((ext_vector_type(8)));
typedef short short4v __attribute__((ext_vector_type(4)));
typedef float f32x4 __attribute__((ext_vector_type(4)));

__device__ __forceinline__ short f2bf(float f) {
  unsigned u = __float_as_uint(f);
  u += 0x7fffu + ((u >> 16) & 1u);   // round-to-nearest-even
  return (short)(u >> 16);
}
__device__ __forceinline__ float bf2f(short s) {
  return __uint_as_float(((unsigned)(unsigned short)s) << 16);
}

typedef __attribute__((address_space(1))) const unsigned int gu32;
typedef __attribute__((address_space(3))) unsigned int lu32;
__device__ __forceinline__ void gl16(const void* g, void* l) {
  __builtin_amdgcn_global_load_lds((gu32*)g, (lu32*)l, 16, 0, 0);
}

// ---------------------------------------------------------------------------
// k1: w = alpha @ beta, stored as bf16 in MFMA-B fragment layout (unchanged)
// ---------------------------------------------------------------------------
__global__ __launch_bounds__(256) void k1_wgen(
    const float* __restrict__ alpha, const float* __restrict__ beta,
    short8* __restrict__ w_frag) {
  const int bid = blockIdx.x;
  const int ngrp = bid >> 1;
  const int ihalf = bid & 1;
  const int t = threadIdx.x;
  const int o = t & 63;
  const int igl = t >> 6;
  const int i0 = ihalf * 32 + igl * 8;
  const int n0 = ngrp * 8;

  float acc[8][8];
#pragma unroll
  for (int r = 0; r < 8; ++r)
#pragma unroll
    for (int j = 0; j < 8; ++j) acc[r][j] = 0.f;

  for (int k = 0; k < CLUSTER; ++k) {
    float av[8];
#pragma unroll
    for (int r = 0; r < 8; ++r) av[r] = alpha[(n0 + r) * CLUSTER + k];
    const float* bp = beta + k * (IN_DIM * OUT_DIM) + i0 * OUT_DIM + o;
#pragma unroll
    for (int j = 0; j < 8; ++j) {
      float bv = bp[j * OUT_DIM];
#pragma unroll
      for (int r = 0; r < 8; ++r) acc[r][j] += av[r] * bv;
    }
  }
#pragma unroll
  for (int r = 0; r < 8; ++r) {
    short8 s;
#pragma unroll
    for (int j = 0; j < 8; ++j) s[j] = f2bf(acc[r][j]);
    w_frag[((n0 + r) * 8 + (i0 >> 3)) * 64 + o] = s;
  }
}

// ---------------------------------------------------------------------------
// k2: h2[b,n,o] = sum_i h[b,n,i]*w[n,i,o] + bias[o]  (unchanged)
// ---------------------------------------------------------------------------
__global__ __launch_bounds__(64) void k2_h2(
    const float* __restrict__ h, const short8* __restrict__ w_frag,
    const float* __restrict__ bias, short* __restrict__ h2_frag) {
  const int n = blockIdx.x;
  const int l = threadIdx.x;
  const int lr = l & 15, lk = l >> 4;

  short8 afr[2][2];
#pragma unroll
  for (int m = 0; m < 2; ++m)
#pragma unroll
    for (int kf = 0; kf < 2; ++kf) {
      const float* hp =
          h + ((size_t)(m * 16 + lr) * NODE + n) * IN_DIM + kf * 32 + lk * 8;
      f32x4 v0 = *(const f32x4*)hp;
      f32x4 v1 = *(const f32x4*)(hp + 4);
      short8 s;
#pragma unroll
      for (int j = 0; j < 4; ++j) { s[j] = f2bf(v0[j]); s[j + 4] = f2bf(v1[j]); }
      afr[m][kf] = s;
    }

  short8 bfr[4][2];
#pragma unroll
  for (int ng = 0; ng < 4; ++ng)
#pragma unroll
    for (int kf = 0; kf < 2; ++kf)
      bfr[ng][kf] = w_frag[(n * 8 + kf * 4 + lk) * 64 + ng * 16 + lr];

  f32x4 acc[2][4];
#pragma unroll
  for (int m = 0; m < 2; ++m)
#pragma unroll
    for (int ng = 0; ng < 4; ++ng) acc[m][ng] = (f32x4){0.f, 0.f, 0.f, 0.f};

#pragma unroll
  for (int kf = 0; kf < 2; ++kf)
#pragma unroll
    for (int m = 0; m < 2; ++m)
#pragma unroll
      for (int ng = 0; ng < 4; ++ng)
        acc[m][ng] = __builtin_amdgcn_mfma_f32_16x16x32_bf16(
            afr[m][kf], bfr[ng][kf], acc[m][ng], 0, 0, 0);

#pragma unroll
  for (int m = 0; m < 2; ++m)
#pragma unroll
    for (int ng = 0; ng < 4; ++ng) {
      const int o = ng * 16 + lr;
      const float bv = bias[o];
#pragma unroll
      for (int r = 0; r < 4; ++r) {
        const int b = m * 16 + lk * 4 + r;
        h2_frag[(((size_t)b * 256 + (n >> 3)) * 64 + o) * 8 + (n & 7)] =
            f2bf(acc[m][ng][r] + bv);
      }
    }
}

// ---------------------------------------------------------------------------
// k3 (hot): out[b] = a[b] @ h2[b] + h2[b]
// A-path restructured for 1-request-per-line: global_load_lds, lane l fetches
// row (l>>3), 16B chunk ((l&7)^(l>>3))  -> each instr = 8 FULL 128B lines.
// LDS tile [32 rows][128B] per wave per 32-K stage, 16B-chunk XOR(row&7)
// swizzle (via pre-swizzled GLOBAL addr, linear LDS dest). Wave-private
// double buffer, lag-1, counted vmcnt(8). No barriers. 4 blocks/CU.
// ---------------------------------------------------------------------------
__global__ __launch_bounds__(256, 4) void k3_main(
    const float* __restrict__ a, const short* __restrict__ h2f,
    float* __restrict__ out) {
  __shared__ float lds[4][2][1024];               // [wave][buf][4 KiB]
  const int bid0 = blockIdx.x;                    // 512
  const int swz = (bid0 & 7) * 64 + (bid0 >> 3);  // XCD-cluster same-batch
  const int b = swz >> 4;                         // 32 batches
  const int rt = swz & 15;                        // 16 row tiles of 128
  const int t = threadIdx.x;
  const int wid = t >> 6;
  const int l = t & 63;
  const int lr = l & 15, lk = l >> 4;
  const int sw = l & 7;                           // = lr & 7
  const int rowbase = rt * 128 + wid * 32;

  // per-lane global A address (gather role: row l>>3 of each 8-row group,
  // chunk (l&7)^(l>>3) -> LDS linear slot l*16 holds swizzled chunk)
  const char* gA = (const char*)(a + (size_t)b * NODE * KDIM
                                   + (size_t)(rowbase + (l >> 3)) * KDIM)
                   + (size_t)(((l & 7) ^ (l >> 3)) * 16);
  const short8* bbase = (const short8*)h2f + ((size_t)b * 256 + lk) * 64 + lr;

  char* ldsb0 = (char*)&lds[wid][0][0];
  char* ldsb1 = (char*)&lds[wid][1][0];
  const int O00 = lr * 128 + ((2 * lk + 0) ^ sw) * 16;
  const int O01 = lr * 128 + ((2 * lk + 1) ^ sw) * 16;
  const int O10 = (16 + lr) * 128 + ((2 * lk + 0) ^ sw) * 16;
  const int O11 = (16 + lr) * 128 + ((2 * lk + 1) ^ sw) * 16;

  f32x4 acc[2][4];
#pragma unroll
  for (int m = 0; m < 2; ++m)
#pragma unroll
    for (int ng = 0; ng < 4; ++ng) acc[m][ng] = (f32x4){0.f, 0.f, 0.f, 0.f};

  short8 BE[4], BO[4];

#define ISSUE_A(s, LP)                                   \
  do {                                                   \
    const char* g_ = gA + (size_t)(s) * 128;             \
    gl16(g_ + 0 * 65536, (LP) + 0 * 1024);               \
    gl16(g_ + 1 * 65536, (LP) + 1 * 1024);               \
    gl16(g_ + 2 * 65536, (LP) + 2 * 1024);               \
    gl16(g_ + 3 * 65536, (LP) + 3 * 1024);               \
  } while (0)

#define ISSUE_B(s, BR)                                   \
  do {                                                   \
    const short8* q_ = bbase + (s) * 256;                \
    BR[0] = q_[0];                                       \
    BR[1] = q_[16];                                      \
    BR[2] = q_[32];                                      \
    BR[3] = q_[48];                                      \
  } while (0)

#define COMPUTE(LP, BR)                                                     \
  do {                                                                      \
    f32x4 m0h0 = *(const f32x4*)((LP) + O00);                               \
    f32x4 m0h1 = *(const f32x4*)((LP) + O01);                               \
    f32x4 m1h0 = *(const f32x4*)((LP) + O10);                               \
    f32x4 m1h1 = *(const f32x4*)((LP) + O11);                               \
    short8 af0, af1;                                                        \
    _Pragma("unroll") for (int j_ = 0; j_ < 4; ++j_) {                      \
      af0[j_] = f2bf(m0h0[j_]);                                             \
      af0[j_ + 4] = f2bf(m0h1[j_]);                                         \
      af1[j_] = f2bf(m1h0[j_]);                                             \
      af1[j_ + 4] = f2bf(m1h1[j_]);                                         \
    }                                                                       \
    _Pragma("unroll") for (int ng_ = 0; ng_ < 4; ++ng_) {                   \
      acc[0][ng_] = __builtin_amdgcn_mfma_f32_16x16x32_bf16(                \
          af0, BR[ng_], acc[0][ng_], 0, 0, 0);                              \
      acc[1][ng_] = __builtin_amdgcn_mfma_f32_16x16x32_bf16(                \
          af1, BR[ng_], acc[1][ng_], 0, 0, 0);                              \
    }                                                                       \
  } while (0)

  // prologue: stage 0 -> buf0/BE
  ISSUE_A(0, ldsb0);
  ISSUE_B(0, BE);

#pragma unroll 1
  for (int u = 0; u < 32; ++u) {
    // even iter te=2u: consume buf0/BE, issue stage te+1 -> buf1/BO
    ISSUE_A(2 * u + 1, ldsb1);
    ISSUE_B(2 * u + 1, BO);
    asm volatile("s_waitcnt vmcnt(8)" ::: "memory");
    __builtin_amdgcn_sched_barrier(0);
    COMPUTE(ldsb0, BE);
    // odd iter to=2u+1: consume buf1/BO, issue stage to+1 -> buf0/BE
    if (u < 31) {
      ISSUE_A(2 * u + 2, ldsb0);
      ISSUE_B(2 * u + 2, BE);
      asm volatile("s_waitcnt vmcnt(8)" ::: "memory");
    } else {
      asm volatile("s_waitcnt vmcnt(0)" ::: "memory");
    }
    __builtin_amdgcn_sched_barrier(0);
    COMPUTE(ldsb1, BO);
  }
#undef ISSUE_A
#undef ISSUE_B
#undef COMPUTE

  // epilogue: residual (+h2) fused; 8-B vector residual reads
#pragma unroll
  for (int m = 0; m < 2; ++m) {
    const int row0 = rowbase + m * 16 + lk * 4;
#pragma unroll
    for (int ng = 0; ng < 4; ++ng) {
      const int col = ng * 16 + lr;
      const short4v rv = *(const short4v*)&h2f[
          (((size_t)b * 256 + (row0 >> 3)) * 64 + col) * 8 + (row0 & 7)];
#pragma unroll
      for (int r = 0; r < 4; ++r) {
        out[((size_t)b * NODE + row0 + r) * 64 + col] =
            acc[m][ng][r] + bf2f(rv[r]);
      }
    }
  }
}

extern "C" void kernel_launch(void* const* d_in, const int* in_sizes, int n_in,
                              void* d_out, int out_size, void* d_ws, size_t ws_size,
                              hipStream_t stream) {
  const float* a     = (const float*)d_in[0];
  const float* h     = (const float*)d_in[1];
  const float* alpha = (const float*)d_in[2];
  const float* beta  = (const float*)d_in[3];
  const float* bias  = (const float*)d_in[4];
  float* out = (float*)d_out;

  short8* w_frag = (short8*)d_ws;
  short*  h2_frag = (short*)((char*)d_ws + (size_t)(16u << 20));

  k1_wgen<<<dim3(512), dim3(256), 0, stream>>>(alpha, beta, w_frag);
  k2_h2 <<<dim3(NODE), dim3(64),  0, stream>>>(h, w_frag, bias, h2_frag);
  k3_main<<<dim3(512), dim3(256), 0, stream>>>(a, h2_frag, out);
}

// Round 5
// 163.199 us; speedup vs baseline: 1.2455x; 1.0660x over previous
//
#include <hip/hip_runtime.h>

#define NODE 2048
#define KDIM 2048
#define CLUSTER 32
#define IN_DIM 64
#define OUT_DIM 64
#define BATCH 32

typedef short short8 __attribute__((ext_vector_type(8)));
typedef short short4v __attribute__((ext_vector_type(4)));
typedef float f32x4 __attribute__((ext_vector_type(4)));

__device__ __forceinline__ short f2bf(float f) {
  unsigned u = __float_as_uint(f);
  u += 0x7fffu + ((u >> 16) & 1u);   // round-to-nearest-even
  return (short)(u >> 16);
}
__device__ __forceinline__ float bf2f(short s) {
  return __uint_as_float(((unsigned)(unsigned short)s) << 16);
}

typedef __attribute__((address_space(1))) const unsigned int gu32;
typedef __attribute__((address_space(3))) unsigned int lu32;
__device__ __forceinline__ void gl16(const void* g, void* l) {
  __builtin_amdgcn_global_load_lds((gu32*)g, (lu32*)l, 16, 0, 0);
}

// ---------------------------------------------------------------------------
// k1: w = alpha @ beta, stored as bf16 in MFMA-B fragment layout (unchanged)
// ---------------------------------------------------------------------------
__global__ __launch_bounds__(256) void k1_wgen(
    const float* __restrict__ alpha, const float* __restrict__ beta,
    short8* __restrict__ w_frag) {
  const int bid = blockIdx.x;
  const int ngrp = bid >> 1;
  const int ihalf = bid & 1;
  const int t = threadIdx.x;
  const int o = t & 63;
  const int igl = t >> 6;
  const int i0 = ihalf * 32 + igl * 8;
  const int n0 = ngrp * 8;

  float acc[8][8];
#pragma unroll
  for (int r = 0; r < 8; ++r)
#pragma unroll
    for (int j = 0; j < 8; ++j) acc[r][j] = 0.f;

  for (int k = 0; k < CLUSTER; ++k) {
    float av[8];
#pragma unroll
    for (int r = 0; r < 8; ++r) av[r] = alpha[(n0 + r) * CLUSTER + k];
    const float* bp = beta + k * (IN_DIM * OUT_DIM) + i0 * OUT_DIM + o;
#pragma unroll
    for (int j = 0; j < 8; ++j) {
      float bv = bp[j * OUT_DIM];
#pragma unroll
      for (int r = 0; r < 8; ++r) acc[r][j] += av[r] * bv;
    }
  }
#pragma unroll
  for (int r = 0; r < 8; ++r) {
    short8 s;
#pragma unroll
    for (int j = 0; j < 8; ++j) s[j] = f2bf(acc[r][j]);
    w_frag[((n0 + r) * 8 + (i0 >> 3)) * 64 + o] = s;
  }
}

// ---------------------------------------------------------------------------
// k2: h2[b,n,o] = sum_i h[b,n,i]*w[n,i,o] + bias[o]  (unchanged)
// ---------------------------------------------------------------------------
__global__ __launch_bounds__(64) void k2_h2(
    const float* __restrict__ h, const short8* __restrict__ w_frag,
    const float* __restrict__ bias, short* __restrict__ h2_frag) {
  const int n = blockIdx.x;
  const int l = threadIdx.x;
  const int lr = l & 15, lk = l >> 4;

  short8 afr[2][2];
#pragma unroll
  for (int m = 0; m < 2; ++m)
#pragma unroll
    for (int kf = 0; kf < 2; ++kf) {
      const float* hp =
          h + ((size_t)(m * 16 + lr) * NODE + n) * IN_DIM + kf * 32 + lk * 8;
      f32x4 v0 = *(const f32x4*)hp;
      f32x4 v1 = *(const f32x4*)(hp + 4);
      short8 s;
#pragma unroll
      for (int j = 0; j < 4; ++j) { s[j] = f2bf(v0[j]); s[j + 4] = f2bf(v1[j]); }
      afr[m][kf] = s;
    }

  short8 bfr[4][2];
#pragma unroll
  for (int ng = 0; ng < 4; ++ng)
#pragma unroll
    for (int kf = 0; kf < 2; ++kf)
      bfr[ng][kf] = w_frag[(n * 8 + kf * 4 + lk) * 64 + ng * 16 + lr];

  f32x4 acc[2][4];
#pragma unroll
  for (int m = 0; m < 2; ++m)
#pragma unroll
    for (int ng = 0; ng < 4; ++ng) acc[m][ng] = (f32x4){0.f, 0.f, 0.f, 0.f};

#pragma unroll
  for (int kf = 0; kf < 2; ++kf)
#pragma unroll
    for (int m = 0; m < 2; ++m)
#pragma unroll
      for (int ng = 0; ng < 4; ++ng)
        acc[m][ng] = __builtin_amdgcn_mfma_f32_16x16x32_bf16(
            afr[m][kf], bfr[ng][kf], acc[m][ng], 0, 0, 0);

#pragma unroll
  for (int m = 0; m < 2; ++m)
#pragma unroll
    for (int ng = 0; ng < 4; ++ng) {
      const int o = ng * 16 + lr;
      const float bv = bias[o];
#pragma unroll
      for (int r = 0; r < 4; ++r) {
        const int b = m * 16 + lk * 4 + r;
        h2_frag[(((size_t)b * 256 + (n >> 3)) * 64 + o) * 8 + (n & 7)] =
            f2bf(acc[m][ng][r] + bv);
      }
    }
}

// ---------------------------------------------------------------------------
// k3 (hot): out[b] = a[b] @ h2[b] + h2[b]
// R3 structure (full-line global_load_lds A-path, wave-private LDS dbuf,
// counted vmcnt(8), no barriers) + PER-WAVE STAGGERED K-START:
// wave g starts its 64-stage K sweep at stage (g*37)&63 and wraps mod 2048.
// Rationale: A's 8KiB row stride aliases any pow2 channel-interleave granule,
// so k-synchronized waves concentrate chip-wide traffic on a small HBM
// channel subset. Staggering decorrelates the k-phase across 2048 waves so
// instantaneous traffic covers all channels.
// ---------------------------------------------------------------------------
__global__ __launch_bounds__(256, 4) void k3_main(
    const float* __restrict__ a, const short* __restrict__ h2f,
    float* __restrict__ out) {
  __shared__ float lds[4][2][1024];               // [wave][buf][4 KiB]
  const int bid0 = blockIdx.x;                    // 512
  const int swz = (bid0 & 7) * 64 + (bid0 >> 3);  // XCD-cluster same-batch
  const int b = swz >> 4;                         // 32 batches
  const int rt = swz & 15;                        // 16 row tiles of 128
  const int t = threadIdx.x;
  const int wid = t >> 6;
  const int l = t & 63;
  const int lr = l & 15, lk = l >> 4;
  const int sw = l & 7;
  const int rowbase = rt * 128 + wid * 32;
  const int s0 = ((swz * 4 + wid) * 37) & 63;     // per-wave K-phase stagger

  const char* gA = (const char*)(a + (size_t)b * NODE * KDIM
                                   + (size_t)(rowbase + (l >> 3)) * KDIM)
                   + (size_t)(((l & 7) ^ (l >> 3)) * 16);
  const short8* bbase = (const short8*)h2f + ((size_t)b * 256 + lk) * 64 + lr;

  char* ldsb0 = (char*)&lds[wid][0][0];
  char* ldsb1 = (char*)&lds[wid][1][0];
  const int O00 = lr * 128 + ((2 * lk + 0) ^ sw) * 16;
  const int O01 = lr * 128 + ((2 * lk + 1) ^ sw) * 16;
  const int O10 = (16 + lr) * 128 + ((2 * lk + 0) ^ sw) * 16;
  const int O11 = (16 + lr) * 128 + ((2 * lk + 1) ^ sw) * 16;

  f32x4 acc[2][4];
#pragma unroll
  for (int m = 0; m < 2; ++m)
#pragma unroll
    for (int ng = 0; ng < 4; ++ng) acc[m][ng] = (f32x4){0.f, 0.f, 0.f, 0.f};

  short8 BE[4], BO[4];

#define ISSUE_A(s, LP)                                   \
  do {                                                   \
    const int ss_ = ((s) + s0) & 63;                     \
    const char* g_ = gA + (size_t)ss_ * 128;             \
    gl16(g_ + 0 * 65536, (LP) + 0 * 1024);               \
    gl16(g_ + 1 * 65536, (LP) + 1 * 1024);               \
    gl16(g_ + 2 * 65536, (LP) + 2 * 1024);               \
    gl16(g_ + 3 * 65536, (LP) + 3 * 1024);               \
  } while (0)

#define ISSUE_B(s, BR)                                   \
  do {                                                   \
    const int ss_ = ((s) + s0) & 63;                     \
    const short8* q_ = bbase + ss_ * 256;                \
    BR[0] = q_[0];                                       \
    BR[1] = q_[16];                                      \
    BR[2] = q_[32];                                      \
    BR[3] = q_[48];                                      \
  } while (0)

#define COMPUTE(LP, BR)                                                     \
  do {                                                                      \
    f32x4 m0h0 = *(const f32x4*)((LP) + O00);                               \
    f32x4 m0h1 = *(const f32x4*)((LP) + O01);                               \
    f32x4 m1h0 = *(const f32x4*)((LP) + O10);                               \
    f32x4 m1h1 = *(const f32x4*)((LP) + O11);                               \
    short8 af0, af1;                                                        \
    _Pragma("unroll") for (int j_ = 0; j_ < 4; ++j_) {                      \
      af0[j_] = f2bf(m0h0[j_]);                                             \
      af0[j_ + 4] = f2bf(m0h1[j_]);                                         \
      af1[j_] = f2bf(m1h0[j_]);                                             \
      af1[j_ + 4] = f2bf(m1h1[j_]);                                         \
    }                                                                       \
    _Pragma("unroll") for (int ng_ = 0; ng_ < 4; ++ng_) {                   \
      acc[0][ng_] = __builtin_amdgcn_mfma_f32_16x16x32_bf16(                \
          af0, BR[ng_], acc[0][ng_], 0, 0, 0);                              \
      acc[1][ng_] = __builtin_amdgcn_mfma_f32_16x16x32_bf16(                \
          af1, BR[ng_], acc[1][ng_], 0, 0, 0);                              \
    }                                                                       \
  } while (0)

  // prologue: stage s0 -> buf0/BE
  ISSUE_A(0, ldsb0);
  ISSUE_B(0, BE);

#pragma unroll 1
  for (int u = 0; u < 32; ++u) {
    ISSUE_A(2 * u + 1, ldsb1);
    ISSUE_B(2 * u + 1, BO);
    asm volatile("s_waitcnt vmcnt(8)" ::: "memory");
    __builtin_amdgcn_sched_barrier(0);
    COMPUTE(ldsb0, BE);
    if (u < 31) {
      ISSUE_A(2 * u + 2, ldsb0);
      ISSUE_B(2 * u + 2, BE);
      asm volatile("s_waitcnt vmcnt(8)" ::: "memory");
    } else {
      asm volatile("s_waitcnt vmcnt(0)" ::: "memory");
    }
    __builtin_amdgcn_sched_barrier(0);
    COMPUTE(ldsb1, BO);
  }
#undef ISSUE_A
#undef ISSUE_B
#undef COMPUTE

  // epilogue: residual (+h2) fused; 8-B vector residual reads
#pragma unroll
  for (int m = 0; m < 2; ++m) {
    const int row0 = rowbase + m * 16 + lk * 4;
#pragma unroll
    for (int ng = 0; ng < 4; ++ng) {
      const int col = ng * 16 + lr;
      const short4v rv = *(const short4v*)&h2f[
          (((size_t)b * 256 + (row0 >> 3)) * 64 + col) * 8 + (row0 & 7)];
#pragma unroll
      for (int r = 0; r < 4; ++r) {
        out[((size_t)b * NODE + row0 + r) * 64 + col] =
            acc[m][ng][r] + bf2f(rv[r]);
      }
    }
  }
}

extern "C" void kernel_launch(void* const* d_in, const int* in_sizes, int n_in,
                              void* d_out, int out_size, void* d_ws, size_t ws_size,
                              hipStream_t stream) {
  const float* a     = (const float*)d_in[0];
  const float* h     = (const float*)d_in[1];
  const float* alpha = (const float*)d_in[2];
  const float* beta  = (const float*)d_in[3];
  const float* bias  = (const float*)d_in[4];
  float* out = (float*)d_out;

  short8* w_frag = (short8*)d_ws;
  short*  h2_frag = (short*)((char*)d_ws + (size_t)(16u << 20));

  k1_wgen<<<dim3(512), dim3(256), 0, stream>>>(alpha, beta, w_frag);
  k2_h2 <<<dim3(NODE), dim3(64),  0, stream>>>(h, w_frag, bias, h2_frag);
  k3_main<<<dim3(512), dim3(256), 0, stream>>>(a, h2_frag, out);
}